// Round 6
// baseline (290.908 us; speedup 1.0000x reference)
//
#include <hip/hip_runtime.h>

#define BB 8
#define SS 512
#define HH 1024
#define NHH 16
#define HDD 64

typedef short short8 __attribute__((ext_vector_type(8)));
typedef float f32x4 __attribute__((ext_vector_type(4)));
typedef unsigned short ushort;

union U4S8 { unsigned u[4]; short8 s; uint4 v; };

// split fp32 pair -> packed bf16 hi (trunc) + bf16 lo (residual, trunc).
// A*B ~= Ah*Bh + Ah*Bl + Al*Bh with ~2^-17 relative error.
__device__ __forceinline__ void split2(float f0, float f1,
                                       unsigned& hi, unsigned& lo)
{
    unsigned u0 = __builtin_bit_cast(unsigned, f0);
    unsigned u1 = __builtin_bit_cast(unsigned, f1);
    hi = __builtin_amdgcn_perm(u1, u0, 0x07060302u);   // [bf16(f1) : bf16(f0)]
    float r0 = f0 - __builtin_bit_cast(float, u0 & 0xffff0000u);
    float r1 = f1 - __builtin_bit_cast(float, u1 & 0xffff0000u);
    unsigned v0 = __builtin_bit_cast(unsigned, r0);
    unsigned v1 = __builtin_bit_cast(unsigned, r1);
    lo = __builtin_amdgcn_perm(v1, v0, 0x07060302u);
}

__device__ __forceinline__ unsigned pack_hi2(float f0, float f1) {
    return __builtin_amdgcn_perm(__builtin_bit_cast(unsigned, f1),
                                 __builtin_bit_cast(unsigned, f0), 0x07060302u);
}
__device__ __forceinline__ ushort bf16_rne(float f) {
    unsigned u = __builtin_bit_cast(unsigned, f);
    u += 0x7fffu + ((u >> 16) & 1u);
    return (ushort)(u >> 16);
}
__device__ __forceinline__ ushort bf16_tr(float f) {
    return (ushort)(__builtin_bit_cast(unsigned, f) >> 16);
}
__device__ __forceinline__ float bf16f(ushort s) {
    unsigned u = ((unsigned)s) << 16;
    return __builtin_bit_cast(float, u);
}
// element index into a swizzled [64][64] bf16 tile (rows stride 128 B);
// 16B-granule XOR by row&7 kills the stride-128 bank conflict (G4).
__device__ __forceinline__ int swel(int row, int col) {
    return row * 64 + ((((col >> 3) ^ (row & 7)) << 3) | (col & 7));
}

// ---------------------------------------------------------------------------
// Kernel 1: fused QKV projection via split-bf16 MFMA (GEMM core validated in
// R2/R5).  Epilogue now emits pre-split hi/lo bf16 planes ([B,NH,S,HD] each);
// Q is pre-scaled by 1/8 (exact) so attention needs no further scaling.
// ---------------------------------------------------------------------------
__global__ __launch_bounds__(256)
void qkv_proj_kernel(const float* __restrict__ HS,
                     const float* __restrict__ Wq, const float* __restrict__ bq,
                     const float* __restrict__ Wk, const float* __restrict__ bk,
                     const float* __restrict__ Wv, const float* __restrict__ bv,
                     ushort* __restrict__ Qh, ushort* __restrict__ Ql,
                     ushort* __restrict__ Kh, ushort* __restrict__ Kl,
                     ushort* __restrict__ Vh, ushort* __restrict__ Vl)
{
    const int bx = blockIdx.x;
    const int by = blockIdx.y;
    const int z   = bx >> 3;
    const int nf0 = (bx & 7) * 128;
    const int m0  = by * 128;

    const float* W    = (z == 0) ? Wq : (z == 1) ? Wk : Wv;
    const float* bias = (z == 0) ? bq : (z == 1) ? bk : bv;
    ushort* OutH = (z == 0) ? Qh : (z == 1) ? Kh : Vh;
    ushort* OutL = (z == 0) ? Ql : (z == 1) ? Kl : Vl;
    const float sc = (z == 0) ? 0.125f : 1.0f;

    __shared__ short Ah[128][32];
    __shared__ short Al[128][32];
    __shared__ short Bh[128][32];
    __shared__ short Bl[128][32];

    const int tid  = threadIdx.x;
    const int lane = tid & 63;
    const int wave = tid >> 6;
    const int wm   = (wave & 1) * 64;
    const int wn   = (wave >> 1) * 64;

    const int srow = tid >> 1;
    const int skh  = (tid & 1) * 16;

    const int fr    = lane & 15;
    const int kslot = lane >> 4;

    f32x4 acc[4][4];
#pragma unroll
    for (int i = 0; i < 4; i++)
#pragma unroll
        for (int j = 0; j < 4; j++) acc[i][j] = (f32x4)0.0f;

    for (int k0 = 0; k0 < HH; k0 += 32) {
        __syncthreads();
        {
            float ra[16], rb[16];
            const float* pa = HS + (size_t)(m0 + srow) * HH + k0 + skh;
            const float* pb = W + (size_t)(nf0 + srow) * HH + k0 + skh;
#pragma unroll
            for (int u = 0; u < 4; u++) {
                *(float4*)&ra[4 * u] = *(const float4*)(pa + 4 * u);
                *(float4*)&rb[4 * u] = *(const float4*)(pb + 4 * u);
            }
            unsigned ha[8], la[8], hb[8], lb[8];
#pragma unroll
            for (int p = 0; p < 8; p++) {
                split2(ra[2 * p], ra[2 * p + 1], ha[p], la[p]);
                split2(rb[2 * p], rb[2 * p + 1], hb[p], lb[p]);
            }
            *(uint4*)&Ah[srow][skh]     = *(uint4*)&ha[0];
            *(uint4*)&Ah[srow][skh + 8] = *(uint4*)&ha[4];
            *(uint4*)&Al[srow][skh]     = *(uint4*)&la[0];
            *(uint4*)&Al[srow][skh + 8] = *(uint4*)&la[4];
            *(uint4*)&Bh[srow][skh]     = *(uint4*)&hb[0];
            *(uint4*)&Bh[srow][skh + 8] = *(uint4*)&hb[4];
            *(uint4*)&Bl[srow][skh]     = *(uint4*)&lb[0];
            *(uint4*)&Bl[srow][skh + 8] = *(uint4*)&lb[4];
        }
        __syncthreads();

        short8 a_h[4], a_l[4], b_h[4], b_l[4];
#pragma unroll
        for (int i = 0; i < 4; i++) {
            a_h[i] = *(const short8*)&Ah[wm + i * 16 + fr][kslot * 8];
            a_l[i] = *(const short8*)&Al[wm + i * 16 + fr][kslot * 8];
            b_h[i] = *(const short8*)&Bh[wn + i * 16 + fr][kslot * 8];
            b_l[i] = *(const short8*)&Bl[wn + i * 16 + fr][kslot * 8];
        }
#pragma unroll
        for (int i = 0; i < 4; i++)
#pragma unroll
            for (int j = 0; j < 4; j++) {
                acc[i][j] = __builtin_amdgcn_mfma_f32_16x16x32_bf16(a_h[i], b_h[j], acc[i][j], 0, 0, 0);
                acc[i][j] = __builtin_amdgcn_mfma_f32_16x16x32_bf16(a_h[i], b_l[j], acc[i][j], 0, 0, 0);
                acc[i][j] = __builtin_amdgcn_mfma_f32_16x16x32_bf16(a_l[i], b_h[j], acc[i][j], 0, 0, 0);
            }
    }

    // epilogue: +bias, (Q only) *1/8, split hi/lo bf16, scatter to planes
    const int cn  = lane & 15;
    const int rm4 = (lane >> 4) * 4;
#pragma unroll
    for (int j = 0; j < 4; j++) {
        const int nn = nf0 + wn + j * 16 + cn;
        const int h  = nn >> 6;
        const int hd = nn & 63;
        const float bval = bias[nn];
#pragma unroll
        for (int i = 0; i < 4; i++) {
            const int mmb = m0 + wm + i * 16 + rm4;
            const int bi  = mmb >> 9;
            const int s0  = mmb & 511;
            const size_t base = (((size_t)(bi * NHH + h) * SS + s0) * HDD + hd);
#pragma unroll
            for (int r = 0; r < 4; r++) {
                const float val = (acc[i][j][r] + bval) * sc;
                const ushort hb = bf16_tr(val);
                const ushort lb2 = bf16_tr(val - bf16f(hb));
                OutH[base + (size_t)r * HDD] = hb;
                OutL[base + (size_t)r * HDD] = lb2;
            }
        }
    }
}

// ---------------------------------------------------------------------------
// Kernel 2: MFMA attention, rolling bias ring.
// Block = (b, h, 64-row q-tile), 512 threads = 8 waves (2 x 4).
// T chunks (64 l x 64 j of q·demb, hi-only operands) computed one per r-tile
// into a 3-slot ring; per r-tile: QK^T (split-3) -> gather T + mask -> exp ->
// split-bf16 P -> PV (split-3) -> compute next T chunk.
// LDS 76.5 KB -> 2 blocks/CU (was 125 KB -> 1).
// ---------------------------------------------------------------------------
__global__ __launch_bounds__(512, 4)
void attn_mfma2_kernel(const ushort* __restrict__ Qh, const ushort* __restrict__ Ql,
                       const ushort* __restrict__ Kh, const ushort* __restrict__ Kl,
                       const ushort* __restrict__ Vh, const ushort* __restrict__ Vl,
                       const float* __restrict__ mask, const float* __restrict__ demb,
                       float* __restrict__ out)
{
    const int qt = blockIdx.x, h = blockIdx.y, b = blockIdx.z;
    const int l0 = qt * 64;
    const int tid  = threadIdx.x;
    const int lane = tid & 63;
    const int wave = tid >> 6;   // 0..7
    const int wl = wave >> 2;    // 0..1 : 32-row half
    const int wr = wave & 3;     // 0..3 : 16-col quarter
    const int fr = lane & 15;
    const int q4 = lane >> 4;
    const int brow = wr * 16 + fr;

    __shared__ short Thf[3 * 64 * 68];            // bias ring: 3 slots [64][68]
    __shared__ short KhS[4096], KlS[4096];        // K tile, swizzled
    __shared__ short VthS[4096], VtlS[4096];      // V^T tile, swizzled
    __shared__ short PhS[4096], PlS[4096];        // P tile, swizzled
    __shared__ float Ms[64];
    __shared__ float rowsumw[4][64];

    const size_t bh = (size_t)(b * NHH + h) * SS * HDD;
    const f32x4 fz = {0.f, 0.f, 0.f, 0.f};

    // ---- persistent Q fragments (already pre-scaled by 1/8, pre-split) ----
    short8 qh[4], ql[4];   // [i*2 + ks]
#pragma unroll
    for (int i = 0; i < 2; i++)
#pragma unroll
        for (int ks = 0; ks < 2; ks++) {
            const size_t off = bh + (size_t)(l0 + wl * 32 + i * 16 + fr) * HDD + ks * 32 + q4 * 8;
            qh[i * 2 + ks] = *(const short8*)(Qh + off);
            ql[i * 2 + ks] = *(const short8*)(Ql + off);
        }

    // ---- T chunk: Thf[slot] = q . demb[l0 + jt*64 + j], hi-only operands ----
    auto chunk = [&](int jt, int slot) {
        f32x4 tacc[2]; tacc[0] = fz; tacc[1] = fz;
#pragma unroll
        for (int ks = 0; ks < 2; ks++) {
            int jrow = l0 + jt * 64 + brow;
            if (jrow > 1022) jrow = 1022;          // clamp (value never gathered)
            const float* ds = demb + (size_t)jrow * HDD + ks * 32 + q4 * 8;
            float4 v0 = *(const float4*)ds;
            float4 v1 = *(const float4*)(ds + 4);
            U4S8 dh;
            dh.u[0] = pack_hi2(v0.x, v0.y); dh.u[1] = pack_hi2(v0.z, v0.w);
            dh.u[2] = pack_hi2(v1.x, v1.y); dh.u[3] = pack_hi2(v1.z, v1.w);
#pragma unroll
            for (int i = 0; i < 2; i++)
                tacc[i] = __builtin_amdgcn_mfma_f32_16x16x32_bf16(qh[i * 2 + ks], dh.s, tacc[i], 0, 0, 0);
        }
#pragma unroll
        for (int i = 0; i < 2; i++)
#pragma unroll
            for (int r = 0; r < 4; r++)
                Thf[slot * 4352 + (wl * 32 + i * 16 + q4 * 4 + r) * 68 + brow] = (short)bf16_rne(tacc[i][r]);
    };

    // prologue: chunks jt=8 (slot 2), jt=7 (slot 1); reads fenced by rt=0 barriers
    chunk(8, 2);
    chunk(7, 1);

    f32x4 ctx[2]; ctx[0] = fz; ctx[1] = fz;
    float rs[2][4] = {{0.f, 0.f, 0.f, 0.f}, {0.f, 0.f, 0.f, 0.f}};

    const int srow = tid >> 3;          // K stage: row, 8 thr/row
    const int sd   = (tid & 7) * 8;
    const int sel  = srow * 64 + (((sd >> 3) ^ (srow & 7)) << 3);
    const int vrow = lane;              // V stage: source row
    const int vd   = wave * 8;          // V stage: d chunk

    for (int rt = 0; rt < 8; rt++) {
        const int r0 = rt * 64;
        __syncthreads();   // A: prev PV reads + prev T-chunk writes settled

        {   // stage K (pre-split planes, swizzled)
            const size_t off = bh + (size_t)(r0 + srow) * HDD + sd;
            *(uint4*)&KhS[sel] = *(const uint4*)(Kh + off);
            *(uint4*)&KlS[sel] = *(const uint4*)(Kl + off);
        }
        {   // stage V transposed [d][r], swizzled
            const size_t off = bh + (size_t)(r0 + vrow) * HDD + vd;
            short8 vh8 = *(const short8*)(Vh + off);
            short8 vl8 = *(const short8*)(Vl + off);
#pragma unroll
            for (int u = 0; u < 8; u++) {
                const int el = swel(vd + u, vrow);
                VthS[el] = vh8[u];
                VtlS[el] = vl8[u];
            }
        }
        if (tid < 64) Ms[tid] = mask[(size_t)b * SS + r0 + tid];
        __syncthreads();   // C

        // ---- QK^T (split-3) ----
        f32x4 sacc[2]; sacc[0] = fz; sacc[1] = fz;
#pragma unroll
        for (int ks = 0; ks < 2; ks++) {
            const int bel = brow * 64 + ((((ks * 4) + q4) ^ (brow & 7)) << 3);
            short8 kh8 = *(const short8*)&KhS[bel];
            short8 kl8 = *(const short8*)&KlS[bel];
#pragma unroll
            for (int i = 0; i < 2; i++) {
                sacc[i] = __builtin_amdgcn_mfma_f32_16x16x32_bf16(qh[i * 2 + ks], kh8, sacc[i], 0, 0, 0);
                sacc[i] = __builtin_amdgcn_mfma_f32_16x16x32_bf16(qh[i * 2 + ks], kl8, sacc[i], 0, 0, 0);
                sacc[i] = __builtin_amdgcn_mfma_f32_16x16x32_bf16(ql[i * 2 + ks], kh8, sacc[i], 0, 0, 0);
            }
        }

        // ---- gather T ring + mask, exp, split-bf16 P ----
#pragma unroll
        for (int i = 0; i < 2; i++)
#pragma unroll
            for (int r = 0; r < 4; r++) {
                const int li  = wl * 32 + i * 16 + q4 * 4 + r;
                const int jjg = li + 511 - (r0 + brow);       // 0..574
                const int jt2 = jjg >> 6;
                const int slot = jt2 - (jt2 >= 3 ? 3 : 0) - (jt2 >= 6 ? 3 : 0);
                const float tb = bf16f((ushort)Thf[slot * 4352 + li * 68 + (jjg & 63)]);
                const float logit = sacc[i][r] + tb + Ms[brow];
                const float p = __expf(logit);
                rs[i][r] += p;
                const ushort phb = bf16_tr(p);
                const float plo = p - bf16f(phb);
                const int el = swel(li, brow);
                PhS[el] = (short)phb;
                PlS[el] = (short)bf16_tr(plo);
            }
        __syncthreads();   // F

        // ---- PV (split-3) ----
#pragma unroll
        for (int ks = 0; ks < 2; ks++) {
            const int belv = brow * 64 + ((((ks * 4) + q4) ^ (brow & 7)) << 3);
            short8 vh8 = *(const short8*)&VthS[belv];
            short8 vl8 = *(const short8*)&VtlS[belv];
#pragma unroll
            for (int i = 0; i < 2; i++) {
                const int arow = wl * 32 + i * 16 + fr;
                const int ael = arow * 64 + ((((ks * 4) + q4) ^ (arow & 7)) << 3);
                short8 ph8 = *(const short8*)&PhS[ael];
                short8 pl8 = *(const short8*)&PlS[ael];
                ctx[i] = __builtin_amdgcn_mfma_f32_16x16x32_bf16(ph8, vh8, ctx[i], 0, 0, 0);
                ctx[i] = __builtin_amdgcn_mfma_f32_16x16x32_bf16(ph8, vl8, ctx[i], 0, 0, 0);
                ctx[i] = __builtin_amdgcn_mfma_f32_16x16x32_bf16(pl8, vh8, ctx[i], 0, 0, 0);
            }
        }

        // ---- compute next T chunk (slot distinct from both gathered this rt) ----
        if (rt < 7) {
            const int jt2 = 6 - rt;
            chunk(jt2, jt2 % 3);
        }
    }

    // ---- row sums: reduce over 16 col-lanes, combine 4 wr slices ----
    __syncthreads();
#pragma unroll
    for (int i = 0; i < 2; i++)
#pragma unroll
        for (int r = 0; r < 4; r++) {
            float v = rs[i][r];
            v += __shfl_xor(v, 1);
            v += __shfl_xor(v, 2);
            v += __shfl_xor(v, 4);
            v += __shfl_xor(v, 8);
            if (fr == 0) rowsumw[wr][wl * 32 + i * 16 + q4 * 4 + r] = v;
        }
    __syncthreads();

#pragma unroll
    for (int i = 0; i < 2; i++)
#pragma unroll
        for (int r = 0; r < 4; r++) {
            const int li = wl * 32 + i * 16 + q4 * 4 + r;
            const float s = rowsumw[0][li] + rowsumw[1][li] + rowsumw[2][li] + rowsumw[3][li];
            out[((size_t)(b * SS + l0 + li)) * HH + h * HDD + wr * 16 + fr] = ctx[i][r] / s;
        }
}

// ---------------------------------------------------------------------------
extern "C" void kernel_launch(void* const* d_in, const int* in_sizes, int n_in,
                              void* d_out, int out_size, void* d_ws, size_t ws_size,
                              hipStream_t stream)
{
    const float* HS   = (const float*)d_in[0];
    const float* mask = (const float*)d_in[1];
    const float* Wq   = (const float*)d_in[2];
    const float* bq   = (const float*)d_in[3];
    const float* Wk   = (const float*)d_in[4];
    const float* bk   = (const float*)d_in[5];
    const float* Wv   = (const float*)d_in[6];
    const float* bv   = (const float*)d_in[7];
    const float* demb = (const float*)d_in[8];
    float* out = (float*)d_out;

    const size_t per = (size_t)BB * NHH * SS * HDD;   // 4,194,304 elements
    ushort* Qh = (ushort*)d_ws;                        // 6 bf16 planes = 48 MB
    ushort* Ql = Qh + per;
    ushort* Kh = Ql + per;
    ushort* Kl = Kh + per;
    ushort* Vh = Kl + per;
    ushort* Vl = Vh + per;

    dim3 gp(24, 32);
    qkv_proj_kernel<<<gp, 256, 0, stream>>>(HS, Wq, bq, Wk, bk, Wv, bv,
                                            Qh, Ql, Kh, Kl, Vh, Vl);

    dim3 ga(SS / 64, NHH, BB);
    attn_mfma2_kernel<<<ga, 512, 0, stream>>>(Qh, Ql, Kh, Kl, Vh, Vl, mask, demb, out);
}